// Round 1
// baseline (5091.209 us; speedup 1.0000x reference)
//
#include <hip/hip_runtime.h>
#include <math.h>

// ---------------- problem dims ----------------
#define BB   512   // batch
#define TT   64    // timesteps
#define AD   6     // action dim
#define HD   256   // obs feature dim
#define RD   256   // recurrent dim
#define LD   1024  // latent dim
#define GD   768   // 3*RD (gate order r,z,n)

// ---------------- workspace layout (float offsets) ----------------
#define OFF_WIHT    0u          // W_ih^T          256x768
#define OFF_WHHT    196608u     // W_hh^T          256x768
#define OFF_WPOSTT  393216u     // W_post^T        512x1024
#define OFF_WCT     917504u     // (W_ih@W_in)^T   1030x768 (row = input col)
#define OFF_BC      1708544u    // b_c = W_ih@b_in + b_ih   768
#define OFF_OBSPROJ 1709312u    // obs_proj        32768x1024
#define WS_FLOATS_FULL (OFF_OBSPROJ + (size_t)32768 * 1024)

__device__ __forceinline__ void fma4(float4& a, const float4 w, const float s) {
  a.x = fmaf(w.x, s, a.x); a.y = fmaf(w.y, s, a.y);
  a.z = fmaf(w.z, s, a.z); a.w = fmaf(w.w, s, a.w);
}

// ---------------- tiled transpose: dst[c*R+r] = src[r*C+c] ----------------
__global__ __launch_bounds__(256) void transpose_k(const float* __restrict__ src,
                                                   float* __restrict__ dst,
                                                   int R, int C) {
  __shared__ float t_s[32][33];
  const int tx = threadIdx.x, ty = threadIdx.y;
  const int c0 = blockIdx.x * 32, r0 = blockIdx.y * 32;
#pragma unroll
  for (int k = 0; k < 4; ++k)
    t_s[ty + k*8][tx] = src[(size_t)(r0 + ty + k*8) * C + c0 + tx];
  __syncthreads();
#pragma unroll
  for (int k = 0; k < 4; ++k)
    dst[(size_t)(c0 + ty + k*8) * R + r0 + tx] = t_s[tx][ty + k*8];
}

// ---------------- W_c = W_ih @ W_in fused-input matrix (transposed) ----------------
// block = one input column (0..1029), col 1030 computes b_c.
__global__ __launch_bounds__(256) void wc_kernel(const float* __restrict__ W_in,
                                                 const float* __restrict__ b_in,
                                                 const float* __restrict__ WihT,
                                                 const float* __restrict__ b_ih,
                                                 float* __restrict__ WcT,
                                                 float* __restrict__ bc) {
  __shared__ float v_s[256];
  const int tid = threadIdx.x;
  const int col = blockIdx.x;           // 0..1030
  v_s[tid] = (col < 1030) ? W_in[(size_t)tid * 1030 + col] : b_in[tid];
  __syncthreads();
  float a0 = 0.f, a1 = 0.f, a2 = 0.f;
#pragma unroll 4
  for (int h = 0; h < 256; ++h) {
    const float v = v_s[h];
    const float* row = &WihT[(size_t)h * GD];
    a0 = fmaf(row[tid      ], v, a0);
    a1 = fmaf(row[tid + 256], v, a1);
    a2 = fmaf(row[tid + 512], v, a2);
  }
  if (col < 1030) {
    WcT[(size_t)col * GD + tid      ] = a0;
    WcT[(size_t)col * GD + tid + 256] = a1;
    WcT[(size_t)col * GD + tid + 512] = a2;
  } else {
    bc[tid      ] = b_ih[tid      ] + a0;
    bc[tid + 256] = b_ih[tid + 256] + a1;
    bc[tid + 512] = b_ih[tid + 512] + a2;
  }
}

// ---------------- obs_proj[m][l] = b_post[l] + sum_h obs[m][h]*W_post[l][256+h] ----
// M=32768, N=1024, K=256. 128x128 tile, BK=32, 8x8 per thread, VALU-bound.
__global__ __launch_bounds__(256) void obsproj_gemm(const float* __restrict__ obs,
                                                    const float* __restrict__ Wpost,
                                                    const float* __restrict__ bpost,
                                                    float* __restrict__ outp) {
  __shared__ __align__(16) float As[32][132];
  __shared__ __align__(16) float Bs[32][132];
  const int tid = threadIdx.x;
  const int tx = tid & 15, ty = tid >> 4;
  const int m0 = blockIdx.y * 128, n0 = blockIdx.x * 128;
  float acc[8][8];
#pragma unroll
  for (int i = 0; i < 8; ++i)
#pragma unroll
    for (int j = 0; j < 8; ++j) acc[i][j] = 0.f;

  for (int k0 = 0; k0 < 256; k0 += 32) {
#pragma unroll
    for (int it = 0; it < 4; ++it) {
      const int idx = tid + it * 256;        // 0..1023
      const int mi = idx >> 3, k4 = (idx & 7) * 4;
      float4 va = *(const float4*)&obs[(size_t)(m0 + mi) * 256 + k0 + k4];
      As[k4+0][mi] = va.x; As[k4+1][mi] = va.y; As[k4+2][mi] = va.z; As[k4+3][mi] = va.w;
      float4 vb = *(const float4*)&Wpost[(size_t)(n0 + mi) * 512 + 256 + k0 + k4];
      Bs[k4+0][mi] = vb.x; Bs[k4+1][mi] = vb.y; Bs[k4+2][mi] = vb.z; Bs[k4+3][mi] = vb.w;
    }
    __syncthreads();
#pragma unroll 8
    for (int k = 0; k < 32; ++k) {
      float4 a0 = *(const float4*)&As[k][ty*4];
      float4 a1 = *(const float4*)&As[k][64 + ty*4];
      float4 b0 = *(const float4*)&Bs[k][tx*4];
      float4 b1 = *(const float4*)&Bs[k][64 + tx*4];
      float av[8] = {a0.x,a0.y,a0.z,a0.w,a1.x,a1.y,a1.z,a1.w};
      float bv[8] = {b0.x,b0.y,b0.z,b0.w,b1.x,b1.y,b1.z,b1.w};
#pragma unroll
      for (int i = 0; i < 8; ++i)
#pragma unroll
        for (int j = 0; j < 8; ++j) acc[i][j] = fmaf(av[i], bv[j], acc[i][j]);
    }
    __syncthreads();
  }
  float4 bp0 = *(const float4*)&bpost[n0 + tx*4];
  float4 bp1 = *(const float4*)&bpost[n0 + 64 + tx*4];
#pragma unroll
  for (int i = 0; i < 8; ++i) {
    const int mi = (i < 4) ? (ty*4 + i) : (64 + ty*4 + (i - 4));
    float4 c0, c1;
    c0.x = acc[i][0] + bp0.x; c0.y = acc[i][1] + bp0.y;
    c0.z = acc[i][2] + bp0.z; c0.w = acc[i][3] + bp0.w;
    c1.x = acc[i][4] + bp1.x; c1.y = acc[i][5] + bp1.y;
    c1.z = acc[i][6] + bp1.z; c1.w = acc[i][7] + bp1.w;
    *(float4*)&outp[(size_t)(m0 + mi) * 1024 + n0 + tx*4] = c0;
    *(float4*)&outp[(size_t)(m0 + mi) * 1024 + n0 + 64 + tx*4] = c1;
  }
}

// ---------------- recurrent scan: 128 blocks x 512 threads, 4 batch/block ----------
__global__ __launch_bounds__(512) void rssm_scan(
    const float* __restrict__ obs, const float* __restrict__ action,
    const int* __restrict__ first, const float* __restrict__ gumbel,
    const float* __restrict__ WhhT, const float* __restrict__ WpostT,
    const float* __restrict__ WcT, const float* __restrict__ bc,
    const float* __restrict__ bhh, const float* __restrict__ bpost,
    const float* __restrict__ obsproj,   // null => fold obs into logits loop
    float* __restrict__ out_deter, float* __restrict__ out_stoch,
    float* __restrict__ out_logits) {
  __shared__ __align__(16) float deter_s[4][256];   // carry h
  __shared__ __align__(16) float gi_s[4][768];
  __shared__ __align__(16) float gh_s[4][768];
  __shared__ __align__(16) float vals_s[4][1056];   // 32 groups * (32+1 pad)
  __shared__ __align__(16) float obs_s[4][256];     // fallback only
  __shared__ float act_s[4][6];
  __shared__ int f_s[4], svalid_s[4], scol_s[4][32];

  const int tid = threadIdx.x;
  const int b0 = blockIdx.x * 4;
  const bool use_op = (obsproj != nullptr);
  const float4* Wc4 = (const float4*)WcT;   // [col][192 float4]
  const float4* Wh4 = (const float4*)WhhT;  // [c][192 float4]
  const float4* Wp4 = (const float4*)WpostT;// [c][256 float4]

  for (int idx = tid; idx < 1024; idx += 512) deter_s[idx >> 8][idx & 255] = 0.f;
  if (tid < 4) svalid_s[tid] = 0;

  for (int t = 0; t < TT; ++t) {
    // ---- S0: load first/action (and obs for fallback) ----
    if (tid < 4) {
      const int f = first[(b0 + tid) * TT + t];
      f_s[tid] = f;
      if (f) svalid_s[tid] = 0;
    }
    if (tid >= 4 && tid < 28) {
      const int q = tid - 4, j = q / 6, a = q % 6;
      act_s[j][a] = action[((size_t)(b0 + j) * TT + t) * AD + a];
    }
    if (!use_op) {
      for (int rep = 0; rep < 2; ++rep) {
        const int idx = tid + rep * 512, j = idx >> 8, r = idx & 255;
        obs_s[j][r] = obs[((size_t)(b0 + j) * TT + t) * HD + r];
      }
    }
    __syncthreads();

    // ---- A: episode reset + gi via gather from W_c (stoch one-hot) ----
    for (int rep = 0; rep < 2; ++rep) {
      const int idx = tid + rep * 512, j = idx >> 8, r = idx & 255;
      if (f_s[j]) deter_s[j][r] = 0.f;
    }
    for (int task = tid; task < 768; task += 512) {
      const int rg = task % 192, j = task / 192;
      float4 acc = *(const float4*)&bc[rg * 4];
#pragma unroll
      for (int a = 0; a < 6; ++a) {
        const float av = act_s[j][a];
        fma4(acc, Wc4[(size_t)(1024 + a) * 192 + rg], av);
      }
      if (svalid_s[j]) {
#pragma unroll 4
        for (int i = 0; i < 32; ++i) {
          const float4 w = Wc4[(size_t)scol_s[j][i] * 192 + rg];
          acc.x += w.x; acc.y += w.y; acc.z += w.z; acc.w += w.w;
        }
      }
      *(float4*)&gi_s[j][rg * 4] = acc;
    }
    __syncthreads();

    // ---- B: gh = W_hh @ deter + b_hh, weight read once per block ----
    if (tid < 192) {
      const float4 bh4 = *(const float4*)&bhh[tid * 4];
      float4 acc0 = bh4, acc1 = bh4, acc2 = bh4, acc3 = bh4;
#pragma unroll 8
      for (int c0 = 0; c0 < 256; c0 += 4) {
        const float4 w0 = Wh4[(size_t)(c0 + 0) * 192 + tid];
        const float4 w1 = Wh4[(size_t)(c0 + 1) * 192 + tid];
        const float4 w2 = Wh4[(size_t)(c0 + 2) * 192 + tid];
        const float4 w3 = Wh4[(size_t)(c0 + 3) * 192 + tid];
        const float4 d0 = *(const float4*)&deter_s[0][c0];
        const float4 d1 = *(const float4*)&deter_s[1][c0];
        const float4 d2 = *(const float4*)&deter_s[2][c0];
        const float4 d3 = *(const float4*)&deter_s[3][c0];
        fma4(acc0, w0, d0.x); fma4(acc0, w1, d0.y); fma4(acc0, w2, d0.z); fma4(acc0, w3, d0.w);
        fma4(acc1, w0, d1.x); fma4(acc1, w1, d1.y); fma4(acc1, w2, d1.z); fma4(acc1, w3, d1.w);
        fma4(acc2, w0, d2.x); fma4(acc2, w1, d2.y); fma4(acc2, w2, d2.z); fma4(acc2, w3, d2.w);
        fma4(acc3, w0, d3.x); fma4(acc3, w1, d3.y); fma4(acc3, w2, d3.z); fma4(acc3, w3, d3.w);
      }
      *(float4*)&gh_s[0][tid * 4] = acc0;
      *(float4*)&gh_s[1][tid * 4] = acc1;
      *(float4*)&gh_s[2][tid * 4] = acc2;
      *(float4*)&gh_s[3][tid * 4] = acc3;
    }
    __syncthreads();

    // ---- G: GRU gates (torch order r,z,n), h overwrites deter ----
    for (int task = tid; task < 1024; task += 512) {
      const int j = task >> 8, r = task & 255;
      const float ir = gi_s[j][r], iz = gi_s[j][r + 256], inn = gi_s[j][r + 512];
      const float hr = gh_s[j][r], hz = gh_s[j][r + 256], hn = gh_s[j][r + 512];
      const float rr = 1.f / (1.f + expf(-(ir + hr)));
      const float zz = 1.f / (1.f + expf(-(iz + hz)));
      const float nn = tanhf(fmaf(rr, hn, inn));
      const float h = (1.f - zz) * nn + zz * deter_s[j][r];
      deter_s[j][r] = h;
      out_deter[((size_t)(b0 + j) * TT + t) * RD + r] = h;
    }
    __syncthreads();

    // ---- C: logits = obs_proj + W_post[:, :256] @ h ; vals = logits + gumbel ----
    if (tid < 256) {
      float4 acc0, acc1, acc2, acc3;
      if (use_op) {
        acc0 = *(const float4*)&obsproj[((size_t)(b0 + 0) * TT + t) * LD + tid * 4];
        acc1 = *(const float4*)&obsproj[((size_t)(b0 + 1) * TT + t) * LD + tid * 4];
        acc2 = *(const float4*)&obsproj[((size_t)(b0 + 2) * TT + t) * LD + tid * 4];
        acc3 = *(const float4*)&obsproj[((size_t)(b0 + 3) * TT + t) * LD + tid * 4];
      } else {
        const float4 bp = *(const float4*)&bpost[tid * 4];
        acc0 = bp; acc1 = bp; acc2 = bp; acc3 = bp;
      }
#pragma unroll 4
      for (int c0 = 0; c0 < 256; c0 += 4) {
        const float4 w0 = Wp4[(size_t)(c0 + 0) * 256 + tid];
        const float4 w1 = Wp4[(size_t)(c0 + 1) * 256 + tid];
        const float4 w2 = Wp4[(size_t)(c0 + 2) * 256 + tid];
        const float4 w3 = Wp4[(size_t)(c0 + 3) * 256 + tid];
        const float4 d0 = *(const float4*)&deter_s[0][c0];
        const float4 d1 = *(const float4*)&deter_s[1][c0];
        const float4 d2 = *(const float4*)&deter_s[2][c0];
        const float4 d3 = *(const float4*)&deter_s[3][c0];
        fma4(acc0, w0, d0.x); fma4(acc0, w1, d0.y); fma4(acc0, w2, d0.z); fma4(acc0, w3, d0.w);
        fma4(acc1, w0, d1.x); fma4(acc1, w1, d1.y); fma4(acc1, w2, d1.z); fma4(acc1, w3, d1.w);
        fma4(acc2, w0, d2.x); fma4(acc2, w1, d2.y); fma4(acc2, w2, d2.z); fma4(acc2, w3, d2.w);
        fma4(acc3, w0, d3.x); fma4(acc3, w1, d3.y); fma4(acc3, w2, d3.z); fma4(acc3, w3, d3.w);
      }
      if (!use_op) {
#pragma unroll 4
        for (int c0 = 0; c0 < 256; c0 += 4) {
          const float4 w0 = Wp4[(size_t)(256 + c0 + 0) * 256 + tid];
          const float4 w1 = Wp4[(size_t)(256 + c0 + 1) * 256 + tid];
          const float4 w2 = Wp4[(size_t)(256 + c0 + 2) * 256 + tid];
          const float4 w3 = Wp4[(size_t)(256 + c0 + 3) * 256 + tid];
          const float4 o0 = *(const float4*)&obs_s[0][c0];
          const float4 o1 = *(const float4*)&obs_s[1][c0];
          const float4 o2 = *(const float4*)&obs_s[2][c0];
          const float4 o3 = *(const float4*)&obs_s[3][c0];
          fma4(acc0, w0, o0.x); fma4(acc0, w1, o0.y); fma4(acc0, w2, o0.z); fma4(acc0, w3, o0.w);
          fma4(acc1, w0, o1.x); fma4(acc1, w1, o1.y); fma4(acc1, w2, o1.z); fma4(acc1, w3, o1.w);
          fma4(acc2, w0, o2.x); fma4(acc2, w1, o2.y); fma4(acc2, w2, o2.z); fma4(acc2, w3, o2.w);
          fma4(acc3, w0, o3.x); fma4(acc3, w1, o3.y); fma4(acc3, w2, o3.z); fma4(acc3, w3, o3.w);
        }
      }
      const int l0 = tid * 4;
      *(float4*)&out_logits[((size_t)(b0 + 0) * TT + t) * LD + l0] = acc0;
      *(float4*)&out_logits[((size_t)(b0 + 1) * TT + t) * LD + l0] = acc1;
      *(float4*)&out_logits[((size_t)(b0 + 2) * TT + t) * LD + l0] = acc2;
      *(float4*)&out_logits[((size_t)(b0 + 3) * TT + t) * LD + l0] = acc3;
      const float4 g0 = *(const float4*)&gumbel[((size_t)t * BB + b0 + 0) * LD + l0];
      const float4 g1 = *(const float4*)&gumbel[((size_t)t * BB + b0 + 1) * LD + l0];
      const float4 g2 = *(const float4*)&gumbel[((size_t)t * BB + b0 + 2) * LD + l0];
      const float4 g3 = *(const float4*)&gumbel[((size_t)t * BB + b0 + 3) * LD + l0];
      const int vb = (l0 >> 5) * 33 + (l0 & 31);  // padded stride-33 group layout
      float* v0 = &vals_s[0][vb]; float* v1 = &vals_s[1][vb];
      float* v2 = &vals_s[2][vb]; float* v3 = &vals_s[3][vb];
      v0[0]=acc0.x+g0.x; v0[1]=acc0.y+g0.y; v0[2]=acc0.z+g0.z; v0[3]=acc0.w+g0.w;
      v1[0]=acc1.x+g1.x; v1[1]=acc1.y+g1.y; v1[2]=acc1.z+g1.z; v1[3]=acc1.w+g1.w;
      v2[0]=acc2.x+g2.x; v2[1]=acc2.y+g2.y; v2[2]=acc2.z+g2.z; v2[3]=acc2.w+g2.w;
      v3[0]=acc3.x+g3.x; v3[1]=acc3.y+g3.y; v3[2]=acc3.z+g3.z; v3[3]=acc3.w+g3.w;
    }
    __syncthreads();

    // ---- D: per-group argmax (first-max wins, matches jnp.argmax) ----
    if (tid < 128) {
      const int j = tid >> 5, g = tid & 31;
      const float* v = &vals_s[j][g * 33];
      float best = v[0]; int bi = 0;
#pragma unroll
      for (int d = 1; d < 32; ++d) {
        const float x = v[d];
        if (x > best) { best = x; bi = d; }
      }
      scol_s[j][g] = g * 32 + bi;
    }
    if (tid < 4) svalid_s[tid] = 1;
    __syncthreads();

    // ---- H: one-hot stoch output ----
    if (tid < 256) {
      const int l0 = tid * 4;
#pragma unroll
      for (int j = 0; j < 4; ++j) {
        const int sc = scol_s[j][l0 >> 5];
        float4 oh;
        oh.x = (sc == l0 + 0) ? 1.f : 0.f;
        oh.y = (sc == l0 + 1) ? 1.f : 0.f;
        oh.z = (sc == l0 + 2) ? 1.f : 0.f;
        oh.w = (sc == l0 + 3) ? 1.f : 0.f;
        *(float4*)&out_stoch[((size_t)(b0 + j) * TT + t) * LD + l0] = oh;
      }
    }
    // no trailing sync needed: next phases that touch shared state are
    // separated from these reads by >=1 __syncthreads().
  }
}

extern "C" void kernel_launch(void* const* d_in, const int* in_sizes, int n_in,
                              void* d_out, int out_size, void* d_ws, size_t ws_size,
                              hipStream_t stream) {
  const float* obs    = (const float*)d_in[0];
  const float* action = (const float*)d_in[1];
  const int*   first  = (const int*)d_in[2];   // bool -> int32 per harness convention
  const float* gumbel = (const float*)d_in[3];
  const float* W_in   = (const float*)d_in[4];
  const float* b_in   = (const float*)d_in[5];
  const float* W_ih   = (const float*)d_in[6];
  const float* W_hh   = (const float*)d_in[7];
  const float* b_ih   = (const float*)d_in[8];
  const float* b_hh   = (const float*)d_in[9];
  const float* W_post = (const float*)d_in[10];
  const float* b_post = (const float*)d_in[11];

  float* ws      = (float*)d_ws;
  float* WihT    = ws + OFF_WIHT;
  float* WhhT    = ws + OFF_WHHT;
  float* WpostT  = ws + OFF_WPOSTT;
  float* WcT     = ws + OFF_WCT;
  float* bc      = ws + OFF_BC;
  float* obsproj = ws + OFF_OBSPROJ;
  const bool use_op = ws_size >= WS_FLOATS_FULL * sizeof(float);

  float* out_deter  = (float*)d_out;
  float* out_stoch  = out_deter + (size_t)BB * TT * RD;
  float* out_logits = out_stoch + (size_t)BB * TT * LD;

  transpose_k<<<dim3(256/32, 768/32), dim3(32, 8), 0, stream>>>(W_ih, WihT, 768, 256);
  transpose_k<<<dim3(256/32, 768/32), dim3(32, 8), 0, stream>>>(W_hh, WhhT, 768, 256);
  transpose_k<<<dim3(512/32, 1024/32), dim3(32, 8), 0, stream>>>(W_post, WpostT, 1024, 512);
  wc_kernel<<<1031, 256, 0, stream>>>(W_in, b_in, WihT, b_ih, WcT, bc);
  if (use_op)
    obsproj_gemm<<<dim3(1024/128, 32768/128), 256, 0, stream>>>(obs, W_post, b_post, obsproj);
  rssm_scan<<<128, 512, 0, stream>>>(obs, action, first, gumbel, WhhT, WpostT, WcT, bc,
                                     b_hh, b_post, use_op ? obsproj : (const float*)nullptr,
                                     out_deter, out_stoch, out_logits);
}

// Round 2
// 3029.348 us; speedup vs baseline: 1.6806x; 1.6806x over previous
//
#include <hip/hip_runtime.h>
#include <math.h>

// ---------------- problem dims ----------------
#define BB   512   // batch
#define TT   64    // timesteps
#define AD   6     // action dim
#define HD   256   // obs feature dim
#define RD   256   // recurrent dim
#define LD   1024  // latent dim
#define GD   768   // 3*RD (gate order r,z,n)

// ---------------- workspace layout (float offsets) ----------------
#define OFF_WIHT    0u          // W_ih^T          256x768
#define OFF_WHHT    196608u     // W_hh^T          256x768
#define OFF_WPOSTT  393216u     // W_post^T        512x1024
#define OFF_WCT     917504u     // (W_ih@W_in)^T   1030x768 (row = input col)
#define OFF_BC      1708544u    // b_c = W_ih@b_in + b_ih   768
#define OFF_OBSPROJ 1709312u    // obs_proj        32768x1024
#define WS_FLOATS_FULL (OFF_OBSPROJ + (size_t)32768 * 1024)

__device__ __forceinline__ void fma4(float4& a, const float4 w, const float s) {
  a.x = fmaf(w.x, s, a.x); a.y = fmaf(w.y, s, a.y);
  a.z = fmaf(w.z, s, a.z); a.w = fmaf(w.w, s, a.w);
}
__device__ __forceinline__ void fma2(float2& a, const float2 w, const float s) {
  a.x = fmaf(w.x, s, a.x); a.y = fmaf(w.y, s, a.y);
}

// ---------------- tiled transpose: dst[c*R+r] = src[r*C+c] ----------------
__global__ __launch_bounds__(256) void transpose_k(const float* __restrict__ src,
                                                   float* __restrict__ dst,
                                                   int R, int C) {
  __shared__ float t_s[32][33];
  const int tx = threadIdx.x, ty = threadIdx.y;
  const int c0 = blockIdx.x * 32, r0 = blockIdx.y * 32;
#pragma unroll
  for (int k = 0; k < 4; ++k)
    t_s[ty + k*8][tx] = src[(size_t)(r0 + ty + k*8) * C + c0 + tx];
  __syncthreads();
#pragma unroll
  for (int k = 0; k < 4; ++k)
    dst[(size_t)(c0 + ty + k*8) * R + r0 + tx] = t_s[tx][ty + k*8];
}

// ---------------- W_c = W_ih @ W_in fused-input matrix (transposed) ----------------
__global__ __launch_bounds__(256) void wc_kernel(const float* __restrict__ W_in,
                                                 const float* __restrict__ b_in,
                                                 const float* __restrict__ WihT,
                                                 const float* __restrict__ b_ih,
                                                 float* __restrict__ WcT,
                                                 float* __restrict__ bc) {
  __shared__ float v_s[256];
  const int tid = threadIdx.x;
  const int col = blockIdx.x;           // 0..1030
  v_s[tid] = (col < 1030) ? W_in[(size_t)tid * 1030 + col] : b_in[tid];
  __syncthreads();
  float a0 = 0.f, a1 = 0.f, a2 = 0.f;
#pragma unroll 4
  for (int h = 0; h < 256; ++h) {
    const float v = v_s[h];
    const float* row = &WihT[(size_t)h * GD];
    a0 = fmaf(row[tid      ], v, a0);
    a1 = fmaf(row[tid + 256], v, a1);
    a2 = fmaf(row[tid + 512], v, a2);
  }
  if (col < 1030) {
    WcT[(size_t)col * GD + tid      ] = a0;
    WcT[(size_t)col * GD + tid + 256] = a1;
    WcT[(size_t)col * GD + tid + 512] = a2;
  } else {
    bc[tid      ] = b_ih[tid      ] + a0;
    bc[tid + 256] = b_ih[tid + 256] + a1;
    bc[tid + 512] = b_ih[tid + 512] + a2;
  }
}

// ---------------- obs_proj[m][l] = b_post[l] + sum_h obs[m][h]*W_post[l][256+h] ----
__global__ __launch_bounds__(256) void obsproj_gemm(const float* __restrict__ obs,
                                                    const float* __restrict__ Wpost,
                                                    const float* __restrict__ bpost,
                                                    float* __restrict__ outp) {
  __shared__ __align__(16) float As[32][132];
  __shared__ __align__(16) float Bs[32][132];
  const int tid = threadIdx.x;
  const int tx = tid & 15, ty = tid >> 4;
  const int m0 = blockIdx.y * 128, n0 = blockIdx.x * 128;
  float acc[8][8];
#pragma unroll
  for (int i = 0; i < 8; ++i)
#pragma unroll
    for (int j = 0; j < 8; ++j) acc[i][j] = 0.f;

  for (int k0 = 0; k0 < 256; k0 += 32) {
#pragma unroll
    for (int it = 0; it < 4; ++it) {
      const int idx = tid + it * 256;        // 0..1023
      const int mi = idx >> 3, k4 = (idx & 7) * 4;
      float4 va = *(const float4*)&obs[(size_t)(m0 + mi) * 256 + k0 + k4];
      As[k4+0][mi] = va.x; As[k4+1][mi] = va.y; As[k4+2][mi] = va.z; As[k4+3][mi] = va.w;
      float4 vb = *(const float4*)&Wpost[(size_t)(n0 + mi) * 512 + 256 + k0 + k4];
      Bs[k4+0][mi] = vb.x; Bs[k4+1][mi] = vb.y; Bs[k4+2][mi] = vb.z; Bs[k4+3][mi] = vb.w;
    }
    __syncthreads();
#pragma unroll 8
    for (int k = 0; k < 32; ++k) {
      float4 a0 = *(const float4*)&As[k][ty*4];
      float4 a1 = *(const float4*)&As[k][64 + ty*4];
      float4 b0 = *(const float4*)&Bs[k][tx*4];
      float4 b1 = *(const float4*)&Bs[k][64 + tx*4];
      float av[8] = {a0.x,a0.y,a0.z,a0.w,a1.x,a1.y,a1.z,a1.w};
      float bv[8] = {b0.x,b0.y,b0.z,b0.w,b1.x,b1.y,b1.z,b1.w};
#pragma unroll
      for (int i = 0; i < 8; ++i)
#pragma unroll
        for (int j = 0; j < 8; ++j) acc[i][j] = fmaf(av[i], bv[j], acc[i][j]);
    }
    __syncthreads();
  }
  float4 bp0 = *(const float4*)&bpost[n0 + tx*4];
  float4 bp1 = *(const float4*)&bpost[n0 + 64 + tx*4];
#pragma unroll
  for (int i = 0; i < 8; ++i) {
    const int mi = (i < 4) ? (ty*4 + i) : (64 + ty*4 + (i - 4));
    float4 c0, c1;
    c0.x = acc[i][0] + bp0.x; c0.y = acc[i][1] + bp0.y;
    c0.z = acc[i][2] + bp0.z; c0.w = acc[i][3] + bp0.w;
    c1.x = acc[i][4] + bp1.x; c1.y = acc[i][5] + bp1.y;
    c1.z = acc[i][6] + bp1.z; c1.w = acc[i][7] + bp1.w;
    *(float4*)&outp[(size_t)(m0 + mi) * 1024 + n0 + tx*4] = c0;
    *(float4*)&outp[(size_t)(m0 + mi) * 1024 + n0 + 64 + tx*4] = c1;
  }
}

// ---------------- recurrent scan: 128 blocks x 1024 threads, 4 batch/block ----------
// Per step, 4 barriers:
//  P1: gh (K-split x2, 384 thr) | gi gather (384 thr) | one-hot(t-1)+obs (256 thr)
//  P2: GRU gates, h update (1024 thr)
//  P3: posterior deter-half dot, K-split x2, float2 grain (1024 thr)
//  P4: combine + logits + gumbel argmax via 8-lane shuffle + stoch idx (1024 thr)
__global__ __launch_bounds__(1024, 4) void rssm_scan(
    const float* __restrict__ obs, const float* __restrict__ action,
    const int* __restrict__ first, const float* __restrict__ gumbel,
    const float* __restrict__ WhhT, const float* __restrict__ WpostT,
    const float* __restrict__ WcT, const float* __restrict__ bc,
    const float* __restrict__ bhh, const float* __restrict__ bpost,
    const float* __restrict__ obsproj,   // null => fold obs into posterior loop
    float* __restrict__ out_deter, float* __restrict__ out_stoch,
    float* __restrict__ out_logits) {
  // gates (P1->P2) and posterior partials (P3->P4) have disjoint lifetimes
  union SharedU {
    struct { float gi[4][GD]; float ghp[2][4][GD]; } g;   // 12KB + 24KB
    float pp[2][4][LD];                                   // 32KB
  };
  __shared__ SharedU u;
  __shared__ __align__(16) float deter_s[4][RD];   // 4KB
  __shared__ __align__(16) float obs_s[4][HD];     // 4KB (fallback only)
  __shared__ float act_all[4][TT][AD];             // 6KB
  __shared__ int   first_all[4][TT];               // 1KB
  __shared__ float bc_s[GD];                       // 3KB
  __shared__ float bhh_s[GD];                      // 3KB
  __shared__ int   scol_s[4][32];

  const int tid = threadIdx.x;
  const int b0 = blockIdx.x * 4;
  const bool use_op = (obsproj != nullptr);
  const float4* Wc4 = (const float4*)WcT;    // [col][192 float4]
  const float4* Wh4 = (const float4*)WhhT;   // [c][192 float4]
  const float2* Wp2 = (const float2*)WpostT; // [c][512 float2]

  // ---- one-time preload ----
  for (int i = tid; i < 1024; i += 1024) deter_s[i >> 8][i & 255] = 0.f;
  for (int i = tid; i < 4 * TT * AD; i += 1024) {
    const int j = i / (TT * AD), rem = i % (TT * AD);
    act_all[j][rem / AD][rem % AD] = action[(size_t)(b0 + j) * TT * AD + rem];
  }
  if (tid < 4 * TT) first_all[tid >> 6][tid & 63] = first[(b0 + (tid >> 6)) * TT + (tid & 63)];
  if (tid < GD) { bc_s[tid] = bc[tid]; bhh_s[tid] = bhh[tid]; }
  __syncthreads();

  const int jme = tid >> 8, o4me = tid & 255;   // P4 / prefetch identity mapping

  for (int t = 0; t < TT; ++t) {
    // ---- register prefetch for P4 (flies under P1..P3) ----
    float4 op4, g4;
    if (use_op)
      op4 = *(const float4*)&obsproj[(((size_t)(b0 + jme) * TT + t) * LD) + o4me * 4];
    else
      op4 = *(const float4*)&bpost[o4me * 4];
    g4 = *(const float4*)&gumbel[(((size_t)t * BB + b0 + jme) * LD) + o4me * 4];

    // ================= P1 =================
    if (tid < 384) {
      // gh: half of K per thread-set; weights read once per block
      const int half = (tid < 192) ? 0 : 1;
      const int rg = tid - half * 192;
      const int cbase = half * 128;
      float4 acc0, acc1, acc2, acc3;
      if (half == 0) {
        acc0 = *(const float4*)&bhh_s[rg * 4];
        acc1 = acc0; acc2 = acc0; acc3 = acc0;
      } else {
        acc0 = make_float4(0.f, 0.f, 0.f, 0.f);
        acc1 = acc0; acc2 = acc0; acc3 = acc0;
      }
#pragma unroll 4
      for (int c = 0; c < 128; c += 4) {
        const float4 w0 = Wh4[(size_t)(cbase + c + 0) * 192 + rg];
        const float4 w1 = Wh4[(size_t)(cbase + c + 1) * 192 + rg];
        const float4 w2 = Wh4[(size_t)(cbase + c + 2) * 192 + rg];
        const float4 w3 = Wh4[(size_t)(cbase + c + 3) * 192 + rg];
        const float4 d0 = *(const float4*)&deter_s[0][cbase + c];
        const float4 d1 = *(const float4*)&deter_s[1][cbase + c];
        const float4 d2 = *(const float4*)&deter_s[2][cbase + c];
        const float4 d3 = *(const float4*)&deter_s[3][cbase + c];
        fma4(acc0, w0, d0.x); fma4(acc0, w1, d0.y); fma4(acc0, w2, d0.z); fma4(acc0, w3, d0.w);
        fma4(acc1, w0, d1.x); fma4(acc1, w1, d1.y); fma4(acc1, w2, d1.z); fma4(acc1, w3, d1.w);
        fma4(acc2, w0, d2.x); fma4(acc2, w1, d2.y); fma4(acc2, w2, d2.z); fma4(acc2, w3, d2.w);
        fma4(acc3, w0, d3.x); fma4(acc3, w1, d3.y); fma4(acc3, w2, d3.z); fma4(acc3, w3, d3.w);
      }
      *(float4*)&u.g.ghp[half][0][rg * 4] = acc0;
      *(float4*)&u.g.ghp[half][1][rg * 4] = acc1;
      *(float4*)&u.g.ghp[half][2][rg * 4] = acc2;
      *(float4*)&u.g.ghp[half][3][rg * 4] = acc3;
    } else if (tid < 768) {
      // gi via gather from W_c (stoch one-hot), 2 tasks/thread
      const int id = tid - 384;
#pragma unroll
      for (int q = 0; q < 2; ++q) {
        const int task = id + q * 384;           // 0..767
        const int j = task / 192, rg = task % 192;
        float4 acc = *(const float4*)&bc_s[rg * 4];
#pragma unroll
        for (int a = 0; a < AD; ++a)
          fma4(acc, Wc4[(size_t)(LD + a) * 192 + rg], act_all[j][t][a]);
        const bool skip = (t == 0) || first_all[j][t];
        if (!skip) {
#pragma unroll 4
          for (int i = 0; i < 32; ++i) {
            const float4 w = Wc4[(size_t)scol_s[j][i] * 192 + rg];
            acc.x += w.x; acc.y += w.y; acc.z += w.z; acc.w += w.w;
          }
        }
        *(float4*)&u.g.gi[j][rg * 4] = acc;
      }
    } else {
      // one-hot stoch store for t-1, obs load (fallback)
      const int z = tid - 768;
      if (t > 0) {
#pragma unroll
        for (int q = 0; q < 4; ++q) {
          const int id = z + q * 256, j = id >> 8, o4 = id & 255;
          const int sc = scol_s[j][o4 >> 3];
          const int l0 = o4 * 4;
          float4 oh;
          oh.x = (sc == l0 + 0) ? 1.f : 0.f;
          oh.y = (sc == l0 + 1) ? 1.f : 0.f;
          oh.z = (sc == l0 + 2) ? 1.f : 0.f;
          oh.w = (sc == l0 + 3) ? 1.f : 0.f;
          *(float4*)&out_stoch[((size_t)(b0 + j) * TT + (t - 1)) * LD + l0] = oh;
        }
      }
      if (!use_op) {
        const int j = z >> 6, r4 = z & 63;
        *(float4*)&obs_s[j][r4 * 4] =
            *(const float4*)&obs[((size_t)(b0 + j) * TT + t) * HD + r4 * 4];
      }
    }
    __syncthreads();

    // ================= P2: GRU gates =================
    {
      const int j = tid >> 8, r = tid & 255;
      const float ir = u.g.gi[j][r], iz = u.g.gi[j][r + 256], inn = u.g.gi[j][r + 512];
      const float hr = u.g.ghp[0][j][r      ] + u.g.ghp[1][j][r      ];
      const float hz = u.g.ghp[0][j][r + 256] + u.g.ghp[1][j][r + 256];
      const float hn = u.g.ghp[0][j][r + 512] + u.g.ghp[1][j][r + 512];
      const bool f = (first_all[j][t] != 0);
      const float dprev = f ? 0.f : deter_s[j][r];
      const float rr = 1.f / (1.f + __expf(-(ir + hr)));
      const float zz = 1.f / (1.f + __expf(-(iz + hz)));
      const float nn = tanhf(fmaf(rr, hn, inn));
      const float h = (1.f - zz) * nn + zz * dprev;
      deter_s[j][r] = h;
      out_deter[((size_t)(b0 + jme) * TT + t) * RD + r] = h;
    }
    __syncthreads();

    // ================= P3: posterior deter-half, K-split x2, float2 =================
    {
      const int half = tid >> 9, o2 = tid & 511;
      const int cbase = half * 128;
      float2 acc0 = make_float2(0.f, 0.f), acc1 = acc0, acc2 = acc0, acc3 = acc0;
#pragma unroll 4
      for (int c = 0; c < 128; c += 4) {
        const float2 w0 = Wp2[(size_t)(cbase + c + 0) * 512 + o2];
        const float2 w1 = Wp2[(size_t)(cbase + c + 1) * 512 + o2];
        const float2 w2 = Wp2[(size_t)(cbase + c + 2) * 512 + o2];
        const float2 w3 = Wp2[(size_t)(cbase + c + 3) * 512 + o2];
        const float4 d0 = *(const float4*)&deter_s[0][cbase + c];
        const float4 d1 = *(const float4*)&deter_s[1][cbase + c];
        const float4 d2 = *(const float4*)&deter_s[2][cbase + c];
        const float4 d3 = *(const float4*)&deter_s[3][cbase + c];
        fma2(acc0, w0, d0.x); fma2(acc0, w1, d0.y); fma2(acc0, w2, d0.z); fma2(acc0, w3, d0.w);
        fma2(acc1, w0, d1.x); fma2(acc1, w1, d1.y); fma2(acc1, w2, d1.z); fma2(acc1, w3, d1.w);
        fma2(acc2, w0, d2.x); fma2(acc2, w1, d2.y); fma2(acc2, w2, d2.z); fma2(acc2, w3, d2.w);
        fma2(acc3, w0, d3.x); fma2(acc3, w1, d3.y); fma2(acc3, w2, d3.z); fma2(acc3, w3, d3.w);
      }
      if (!use_op) {
        // fold obs half: rows 256..511 of WpostT
#pragma unroll 4
        for (int c = 0; c < 128; c += 4) {
          const float2 w0 = Wp2[(size_t)(256 + cbase + c + 0) * 512 + o2];
          const float2 w1 = Wp2[(size_t)(256 + cbase + c + 1) * 512 + o2];
          const float2 w2 = Wp2[(size_t)(256 + cbase + c + 2) * 512 + o2];
          const float2 w3 = Wp2[(size_t)(256 + cbase + c + 3) * 512 + o2];
          const float4 o0 = *(const float4*)&obs_s[0][cbase + c];
          const float4 o1 = *(const float4*)&obs_s[1][cbase + c];
          const float4 o2v = *(const float4*)&obs_s[2][cbase + c];
          const float4 o3 = *(const float4*)&obs_s[3][cbase + c];
          fma2(acc0, w0, o0.x); fma2(acc0, w1, o0.y); fma2(acc0, w2, o0.z); fma2(acc0, w3, o0.w);
          fma2(acc1, w0, o1.x); fma2(acc1, w1, o1.y); fma2(acc1, w2, o1.z); fma2(acc1, w3, o1.w);
          fma2(acc2, w0, o2v.x); fma2(acc2, w1, o2v.y); fma2(acc2, w2, o2v.z); fma2(acc2, w3, o2v.w);
          fma2(acc3, w0, o3.x); fma2(acc3, w1, o3.y); fma2(acc3, w2, o3.z); fma2(acc3, w3, o3.w);
        }
      }
      *(float2*)&u.pp[half][0][o2 * 2] = acc0;
      *(float2*)&u.pp[half][1][o2 * 2] = acc1;
      *(float2*)&u.pp[half][2][o2 * 2] = acc2;
      *(float2*)&u.pp[half][3][o2 * 2] = acc3;
    }
    __syncthreads();

    // ================= P4: logits + gumbel argmax (8-lane shuffle) =================
    {
      const float4 p0 = *(const float4*)&u.pp[0][jme][o4me * 4];
      const float4 p1 = *(const float4*)&u.pp[1][jme][o4me * 4];
      float4 l;
      l.x = p0.x + p1.x + op4.x; l.y = p0.y + p1.y + op4.y;
      l.z = p0.z + p1.z + op4.z; l.w = p0.w + p1.w + op4.w;
      *(float4*)&out_logits[((size_t)(b0 + jme) * TT + t) * LD + o4me * 4] = l;
      float v[4] = {l.x + g4.x, l.y + g4.y, l.z + g4.z, l.w + g4.w};
      float mv = v[0]; int mi = o4me * 4;
#pragma unroll
      for (int i = 1; i < 4; ++i)
        if (v[i] > mv) { mv = v[i]; mi = o4me * 4 + i; }
#pragma unroll
      for (int off = 1; off < 8; off <<= 1) {
        const float ov = __shfl_xor(mv, off);
        const int   oi = __shfl_xor(mi, off);
        if (ov > mv || (ov == mv && oi < mi)) { mv = ov; mi = oi; }
      }
      if ((o4me & 7) == 0) scol_s[jme][o4me >> 3] = mi;   // mi in [g*32, g*32+32)
      // reset deter for t+1 episode starts (before P1(t+1) reads it)
      if (tid < 256) {
        const int j2 = tid >> 6, r4 = tid & 63;
        if (t + 1 < TT && first_all[j2][t + 1])
          *(float4*)&deter_s[j2][r4 * 4] = make_float4(0.f, 0.f, 0.f, 0.f);
      }
    }
    __syncthreads();
  }

  // tail: one-hot stoch for t=63
  {
    const int sc = scol_s[jme][o4me >> 3];
    const int l0 = o4me * 4;
    float4 oh;
    oh.x = (sc == l0 + 0) ? 1.f : 0.f;
    oh.y = (sc == l0 + 1) ? 1.f : 0.f;
    oh.z = (sc == l0 + 2) ? 1.f : 0.f;
    oh.w = (sc == l0 + 3) ? 1.f : 0.f;
    *(float4*)&out_stoch[((size_t)(b0 + jme) * TT + (TT - 1)) * LD + l0] = oh;
  }
}

extern "C" void kernel_launch(void* const* d_in, const int* in_sizes, int n_in,
                              void* d_out, int out_size, void* d_ws, size_t ws_size,
                              hipStream_t stream) {
  const float* obs    = (const float*)d_in[0];
  const float* action = (const float*)d_in[1];
  const int*   first  = (const int*)d_in[2];
  const float* gumbel = (const float*)d_in[3];
  const float* W_in   = (const float*)d_in[4];
  const float* b_in   = (const float*)d_in[5];
  const float* W_ih   = (const float*)d_in[6];
  const float* W_hh   = (const float*)d_in[7];
  const float* b_ih   = (const float*)d_in[8];
  const float* b_hh   = (const float*)d_in[9];
  const float* W_post = (const float*)d_in[10];
  const float* b_post = (const float*)d_in[11];

  float* ws      = (float*)d_ws;
  float* WihT    = ws + OFF_WIHT;
  float* WhhT    = ws + OFF_WHHT;
  float* WpostT  = ws + OFF_WPOSTT;
  float* WcT     = ws + OFF_WCT;
  float* bc      = ws + OFF_BC;
  float* obsproj = ws + OFF_OBSPROJ;
  const bool use_op = ws_size >= WS_FLOATS_FULL * sizeof(float);

  float* out_deter  = (float*)d_out;
  float* out_stoch  = out_deter + (size_t)BB * TT * RD;
  float* out_logits = out_stoch + (size_t)BB * TT * LD;

  transpose_k<<<dim3(256/32, 768/32), dim3(32, 8), 0, stream>>>(W_ih, WihT, 768, 256);
  transpose_k<<<dim3(256/32, 768/32), dim3(32, 8), 0, stream>>>(W_hh, WhhT, 768, 256);
  transpose_k<<<dim3(512/32, 1024/32), dim3(32, 8), 0, stream>>>(W_post, WpostT, 1024, 512);
  wc_kernel<<<1031, 256, 0, stream>>>(W_in, b_in, WihT, b_ih, WcT, bc);
  if (use_op)
    obsproj_gemm<<<dim3(1024/128, 32768/128), 256, 0, stream>>>(obs, W_post, b_post, obsproj);
  rssm_scan<<<128, 1024, 0, stream>>>(obs, action, first, gumbel, WhhT, WpostT, WcT, bc,
                                      b_hh, b_post, use_op ? obsproj : (const float*)nullptr,
                                      out_deter, out_stoch, out_logits);
}